// Round 4
// baseline (419.905 us; speedup 1.0000x reference)
//
#include <hip/hip_runtime.h>

#define DIM 256
#define PDIM 260          // f32 LDS row stride (2-way banks = free)
#define PD2  264          // bf16 LDS row stride (528 B, 16B-aligned, 2-way banks)
#define NNB 24
#define NEL 8192
#define ROWS 16
#define NT 512
#define CUTOFF 5.0f

typedef unsigned int u32;
typedef unsigned short u16;
typedef __attribute__((ext_vector_type(8))) short bf16x8;
typedef __attribute__((ext_vector_type(4))) float f32x4;

__device__ __forceinline__ u16 f2b(float f){
  union{float f;u32 i;}v; v.f=f;
  u32 r = v.i + 0x7fffu + ((v.i>>16)&1u);   // RNE
  return (u16)(r>>16);
}
__device__ __forceinline__ float b2f(u16 u){
  union{u32 i;float f;}v; v.i = ((u32)u)<<16; return v.f;
}
__device__ __forceinline__ float fast_silu(float x){
  float e = __builtin_amdgcn_exp2f(-1.44269504088896340f * x);
  return x * __builtin_amdgcn_rcpf(1.0f + e);
}

// Pre-pass. Blocks 0..1023: Wt[mat][n][k] = bf16(W[k][n]) (4 x 256x256).
// Block 1024: Wcat[n][kk] = bf16(kk<16 ? Wsame[kk][n] : Wdiff[kk-16][n])  (256x32).
__global__ __launch_bounds__(256)
void wprep(const float* __restrict__ W0, const float* __restrict__ W1,
           const float* __restrict__ W2, const float* __restrict__ W3,
           const float* __restrict__ Wsame, const float* __restrict__ Wdiff,
           u16* __restrict__ ws){
  if (blockIdx.x < 1024){
    const int mat = blockIdx.x >> 8;
    const int n   = blockIdx.x & 255;
    const int k   = threadIdx.x;
    const float* W = (mat==0)?W0:(mat==1)?W1:(mat==2)?W2:W3;
    ws[(mat<<16) + (n<<8) + k] = f2b(W[(k<<8) + n]);
  } else {
    const int n = threadIdx.x;
    u16* dst = ws + 4*65536 + n*32;
    #pragma unroll
    for (int kk = 0; kk < 16; kk++){
      dst[kk]    = f2b(Wsame[kk*DIM + n]);
      dst[16+kk] = f2b(Wdiff[kk*DIM + n]);
    }
  }
}

// MFMA GEMM: C[16][256] = f(A[16][256] @ W + bias ...).  Wt = bf16 W^T [n][k].
// ABF16: A is bf16 LDS stride PD2; else f32 LDS stride PDIM.
// MODE 0: silu(.)            -> sE1b (bf16)
// MODE 1: silu(. + sR1)      -> sR1
// MODE 2: silu(. + msg gbl), inner barrier, -> sR1
// MODE 3: (silu(.) + b2f(sE1b)) * scl -> outGbl
template<int MODE, int ABF16>
__device__ __forceinline__ void gemm_mfma(
    const void* A, u16* sE1b, float* sR1,
    const u16* __restrict__ Wt, const float* __restrict__ bias,
    const float* __restrict__ extraGbl, float* __restrict__ outGbl,
    float scl, int n0, int t)
{
  const int lane = t & 63;
  const int ln   = lane & 15;
  const int quad = lane >> 4;
  const int nt0  = (t >> 6) << 1;
  f32x4 acc0 = {0.f,0.f,0.f,0.f};
  f32x4 acc1 = {0.f,0.f,0.f,0.f};
  const u16* bp0 = Wt + (nt0*16 + ln)*DIM;
  const u16* bp1 = bp0 + 16*DIM;
  #pragma unroll
  for (int ks = 0; ks < 8; ks++){
    const int k0 = ks*32 + quad*8;
    bf16x8 af;
    if (ABF16){
      af = *(const bf16x8*)((const u16*)A + ln*PD2 + k0);
    } else {
      const float* arow = (const float*)A + ln*PDIM;
      float4 a01 = *(const float4*)(arow + k0);
      float4 a23 = *(const float4*)(arow + k0 + 4);
      af[0]=(short)f2b(a01.x); af[1]=(short)f2b(a01.y);
      af[2]=(short)f2b(a01.z); af[3]=(short)f2b(a01.w);
      af[4]=(short)f2b(a23.x); af[5]=(short)f2b(a23.y);
      af[6]=(short)f2b(a23.z); af[7]=(short)f2b(a23.w);
    }
    bf16x8 b0 = *(const bf16x8*)(bp0 + k0);
    bf16x8 b1 = *(const bf16x8*)(bp1 + k0);
    acc0 = __builtin_amdgcn_mfma_f32_16x16x32_bf16(af, b0, acc0, 0, 0, 0);
    acc1 = __builtin_amdgcn_mfma_f32_16x16x32_bf16(af, b1, acc1, 0, 0, 0);
  }
  if (MODE == 2) __syncthreads();   // all k-loop reads of sR1 done before overwrite
  #pragma unroll
  for (int r = 0; r < 4; r++){
    const int m = quad*4 + r;
    #pragma unroll
    for (int tt = 0; tt < 2; tt++){
      const int n = (nt0+tt)*16 + ln;
      float v = (tt ? acc1[r] : acc0[r]) + bias[n];
      if (MODE == 1) v += sR1[m*PDIM + n];
      if (MODE == 2) v += extraGbl[(size_t)(n0+m)*DIM + n];
      v = fast_silu(v);
      if (MODE == 0)      sE1b[m*PD2 + n] = f2b(v);
      else if (MODE == 3) outGbl[(size_t)(n0+m)*DIM + n] = (v + b2f(sE1b[m*PD2 + n])) * scl;
      else                sR1[m*PDIM + n] = v;
    }
  }
}

__global__ __launch_bounds__(NT, 6)
void fused_moon_kernel(
    const float* __restrict__ elec, const float* __restrict__ msg,
    const float* __restrict__ rpos, const float* __restrict__ rnb,
    const int* __restrict__ s,    const int* __restrict__ snb,
    const float* __restrict__ hinit,
    const float* __restrict__ bin,
    const float* __restrict__ eesc, const float* __restrict__ eek,
    const float* __restrict__ eeb,  const float* __restrict__ Wf,
    const float* __restrict__ bfb,
    const float* __restrict__ b1, const float* __restrict__ b2,
    const float* __restrict__ b3,
    const float* __restrict__ scalep,
    const u16* __restrict__ Wt,     // ws: 4x[256][256] bf16 + Wcat[256][32]
    float* __restrict__ out)
{
  __shared__ float sR1[ROWS*PDIM];        // elec -> hmsg -> t1 -> t2
  __shared__ u16   sE1b[ROWS*PD2];        // elec1 (bf16)
  __shared__ u16   sBC[NNB*16*32];        // betaCat bf16, chunk-swizzled
  const int t  = threadIdx.x;
  const int n0 = blockIdx.x * ROWS;

  // ---- Phase 0: stage elec rows into sR1 ----
  {
    const float4* ep = (const float4*)elec;
    #pragma unroll
    for (int h = 0; h < 2; h++){
      const int idx = t + h*NT;                 // 16 rows x 64 float4
      float4 v = ep[(size_t)n0*64 + idx];
      *(float4*)&sR1[(idx>>6)*PDIM + (idx&63)*4] = v;
    }
  }
  __syncthreads();

  // ---- GEMM1: elec1 = silu(elec @ W_in + b_in) -> sE1b ----
  gemm_mfma<0,0>(sR1, sE1b, sR1, Wt, bin, nullptr, nullptr, 0.f, n0, t);

  // ---- Phase 2a: pairwise filter -> betaCat (bf16, mask-folded) ----
  if (t < ROWS*NNB) {
    const int rr = t / NNB;
    const int k  = t - rr*NNB;
    const int n  = n0 + rr;
    const float* rp  = rpos + n*3;
    const float* rnp = rnb + (n*NNB + k)*3;
    float dx = rnp[0] - rp[0];
    float dy = rnp[1] - rp[1];
    float dz = rnp[2] - rp[2];
    float dist = sqrtf(dx*dx + dy*dy + dz*dz + 1e-12f);
    float feats[4] = {dist, dx, dy, dz};
    float h[32];
    #pragma unroll
    for (int f4 = 0; f4 < 8; f4++){
      float4 a4 = *(const float4*)&eeb[4*f4];
      float av[4] = {a4.x, a4.y, a4.z, a4.w};
      #pragma unroll
      for (int i = 0; i < 4; i++){
        float4 kv = *(const float4*)&eek[i*32 + 4*f4];
        av[0]+=feats[i]*kv.x; av[1]+=feats[i]*kv.y; av[2]+=feats[i]*kv.z; av[3]+=feats[i]*kv.w;
      }
      h[4*f4+0]=fast_silu(av[0]); h[4*f4+1]=fast_silu(av[1]);
      h[4*f4+2]=fast_silu(av[2]); h[4*f4+3]=fast_silu(av[3]);
    }
    float env[8];
    #pragma unroll
    for (int e = 0; e < 8; e++){
      float q = dist * __builtin_amdgcn_rcpf(eesc[e]);
      env[e] = __builtin_amdgcn_exp2f(-1.44269504088896340f * q * q);
    }
    float xx = dist * (1.0f/CUTOFF);
    float cut = (dist < CUTOFF) ? (1.0f-xx)*(1.0f-xx)*(1.0f+2.0f*xx) : 0.0f;
    float barr[16];
    #pragma unroll
    for (int j4 = 0; j4 < 4; j4++){
      float4 a4 = *(const float4*)&bfb[4*j4];
      float av[4] = {a4.x, a4.y, a4.z, a4.w};
      #pragma unroll
      for (int f = 0; f < 40; f++){
        float val = (f < 32) ? h[f] : env[f-32];
        float4 wv = *(const float4*)&Wf[f*16 + 4*j4];
        av[0]+=val*wv.x; av[1]+=val*wv.y; av[2]+=val*wv.z; av[3]+=val*wv.w;
      }
      barr[4*j4+0]=av[0]*cut; barr[4*j4+1]=av[1]*cut;
      barr[4*j4+2]=av[2]*cut; barr[4*j4+3]=av[3]*cut;
    }
    const int m = (s[n] == snb[n*NNB + k]);
    u16 vals[32];
    #pragma unroll
    for (int j = 0; j < 16; j++){
      u16 b = f2b(barr[j]);
      vals[j]    = m ? b : (u16)0;
      vals[16+j] = m ? (u16)0 : b;
    }
    u16* rowp = &sBC[(k*16 + rr)*32];
    #pragma unroll
    for (int c = 0; c < 4; c++){
      const int cp = c ^ ((rr>>1)&3);           // chunk swizzle -> 2-way banks on read
      bf16x8 cv;
      #pragma unroll
      for (int j = 0; j < 8; j++) cv[j] = (short)vals[c*8 + j];
      *(bf16x8*)(rowp + cp*8) = cv;
    }
  }
  __syncthreads();   // sE1b + betaCat ready; GEMM1 reads of sR1 done

  // ---- Phase 2b: gamma via MFMA (K=32 concat), fused silu(e1+hinit)*gamma ----
  {
    const int lane = t & 63;
    const int ln   = lane & 15;
    const int quad = lane >> 4;
    const int nt0  = (t >> 6) << 1;
    const u16* Wcat = Wt + 4*65536;
    bf16x8 bs0 = *(const bf16x8*)(Wcat + (nt0*16 + ln)*32 + quad*8);
    bf16x8 bs1 = *(const bf16x8*)(Wcat + ((nt0+1)*16 + ln)*32 + quad*8);
    float e1v[4][2], hm[4][2];
    #pragma unroll
    for (int j = 0; j < 4; j++){
      #pragma unroll
      for (int tt = 0; tt < 2; tt++){
        e1v[j][tt] = b2f(sE1b[(quad*4+j)*PD2 + (nt0+tt)*16 + ln]);
        hm[j][tt] = 0.f;
      }
    }
    const int cswz = (quad ^ ((ln>>1)&3))*8;
    const float* hb = hinit + (size_t)(n0 + quad*4)*NNB*DIM + ln;
    for (int k = 0; k < NNB; k++){
      bf16x8 af = *(const bf16x8*)(&sBC[(k*16 + ln)*32 + cswz]);
      f32x4 z = {0.f,0.f,0.f,0.f};
      f32x4 g0 = __builtin_amdgcn_mfma_f32_16x16x32_bf16(af, bs0, z, 0, 0, 0);
      f32x4 g1 = __builtin_amdgcn_mfma_f32_16x16x32_bf16(af, bs1, z, 0, 0, 0);
      #pragma unroll
      for (int j = 0; j < 4; j++){
        const float* hp = hb + ((size_t)(j*NNB + k))*DIM + nt0*16;
        float h0 = hp[0];
        float h1 = hp[16];
        hm[j][0] += fast_silu(e1v[j][0] + h0) * g0[j];
        hm[j][1] += fast_silu(e1v[j][1] + h1) * g1[j];
      }
    }
    #pragma unroll
    for (int j = 0; j < 4; j++){
      sR1[(quad*4+j)*PDIM + nt0*16 + ln]     = hm[j][0];
      sR1[(quad*4+j)*PDIM + (nt0+1)*16 + ln] = hm[j][1];
    }
  }
  __syncthreads();

  const float scl = scalep[0];

  // ---- GEMM2: t1 = silu(elec1 @ W1 + b1 + hmsg) -> sR1 ----
  gemm_mfma<1,1>(sE1b, sE1b, sR1, Wt + (1<<16), b1, nullptr, nullptr, 0.f, n0, t);
  __syncthreads();
  // ---- GEMM3: t2 = silu(t1 @ W2 + b2 + msg) -> sR1 (inner barrier) ----
  gemm_mfma<2,0>(sR1, sE1b, sR1, Wt + (2<<16), b2, msg, nullptr, 0.f, n0, t);
  __syncthreads();
  // ---- GEMM4: out = (silu(t2 @ W3 + b3) + elec1) * scl ----
  gemm_mfma<3,0>(sR1, sE1b, sR1, Wt + (3<<16), b3, nullptr, out, scl, n0, t);
}

extern "C" void kernel_launch(void* const* d_in, const int* in_sizes, int n_in,
                              void* d_out, int out_size, void* d_ws, size_t ws_size,
                              hipStream_t stream) {
  (void)in_sizes; (void)n_in; (void)ws_size; (void)out_size;
  const float* elec  = (const float*)d_in[0];
  const float* msg   = (const float*)d_in[1];
  const float* rpos  = (const float*)d_in[2];
  const float* rnb   = (const float*)d_in[3];
  const int*   s     = (const int*)d_in[4];
  const int*   snb   = (const int*)d_in[5];
  const float* hinit = (const float*)d_in[6];
  const float* Win   = (const float*)d_in[7];
  const float* bin   = (const float*)d_in[8];
  const float* eesc  = (const float*)d_in[9];
  const float* eek   = (const float*)d_in[10];
  const float* eeb   = (const float*)d_in[11];
  const float* Wf    = (const float*)d_in[12];
  const float* bfb   = (const float*)d_in[13];
  const float* Wsame = (const float*)d_in[14];
  const float* Wdiff = (const float*)d_in[15];
  const float* W1    = (const float*)d_in[16];
  const float* b1    = (const float*)d_in[17];
  const float* W2    = (const float*)d_in[18];
  const float* b2    = (const float*)d_in[19];
  const float* W3    = (const float*)d_in[20];
  const float* b3    = (const float*)d_in[21];
  const float* scl   = (const float*)d_in[22];
  float* outp        = (float*)d_out;
  u16*   wt          = (u16*)d_ws;       // 528 KB used

  wprep<<<dim3(1025), dim3(256), 0, stream>>>(Win, W1, W2, W3, Wsame, Wdiff, wt);
  fused_moon_kernel<<<dim3(NEL/ROWS), dim3(NT), 0, stream>>>(
      elec, msg, rpos, rnb, s, snb, hinit,
      bin, eesc, eek, eeb, Wf, bfb,
      b1, b2, b3, scl, wt, outp);
}

// Round 5
// 370.508 us; speedup vs baseline: 1.1333x; 1.1333x over previous
//
#include <hip/hip_runtime.h>

#define DIM 256
#define PDIM 260          // f32 LDS row stride
#define PD2  264          // bf16 LDS row stride
#define SBPITCH 20        // sBC row stride (u16)
#define SGPITCH 40        // sG row stride (f32) — 160 B, 16B aligned
#define NNB 24
#define NEL 8192
#define ROWS 16
#define NT 512
#define CUTOFF 5.0f

typedef unsigned int u32;
typedef unsigned short u16;
typedef __attribute__((ext_vector_type(8))) short bf16x8;
typedef __attribute__((ext_vector_type(4))) float f32x4;

__device__ __forceinline__ u16 f2b(float f){
  union{float f;u32 i;}v; v.f=f;
  u32 r = v.i + 0x7fffu + ((v.i>>16)&1u);   // RNE
  return (u16)(r>>16);
}
__device__ __forceinline__ float b2f(u16 u){
  union{u32 i;float f;}v; v.i = ((u32)u)<<16; return v.f;
}
__device__ __forceinline__ float fast_silu(float x){
  float e = __builtin_amdgcn_exp2f(-1.44269504088896340f * x);
  return x * __builtin_amdgcn_rcpf(1.0f + e);
}

// Pre-pass. Blocks 0..1023: Wt[mat][n][k] = bf16(W[k][n]) (4 x 256x256).
// Block 1024: Wcat[n][kk] = bf16(kk<16 ? Wsame[kk][n] : Wdiff[kk-16][n])  (256x32).
__global__ __launch_bounds__(256)
void wprep(const float* __restrict__ W0, const float* __restrict__ W1,
           const float* __restrict__ W2, const float* __restrict__ W3,
           const float* __restrict__ Wsame, const float* __restrict__ Wdiff,
           u16* __restrict__ ws){
  if (blockIdx.x < 1024){
    const int mat = blockIdx.x >> 8;
    const int n   = blockIdx.x & 255;
    const int k   = threadIdx.x;
    const float* W = (mat==0)?W0:(mat==1)?W1:(mat==2)?W2:W3;
    ws[(mat<<16) + (n<<8) + k] = f2b(W[(k<<8) + n]);
  } else {
    const int n = threadIdx.x;
    u16* dst = ws + 4*65536 + n*32;
    #pragma unroll
    for (int kk = 0; kk < 16; kk++){
      dst[kk]    = f2b(Wsame[kk*DIM + n]);
      dst[16+kk] = f2b(Wdiff[kk*DIM + n]);
    }
  }
}

// MFMA GEMM: C[16][256] = f(A[16][256] @ W + bias ...).  Wt = bf16 W^T [n][k].
// ABF16: A is bf16 LDS stride PD2; else f32 LDS stride PDIM.
// MODE 0: silu(.)            -> sE1b (bf16)
// MODE 1: silu(. + sR1)      -> sR1   (in-place per-element owner)
// MODE 2: silu(. + msg gbl), inner barrier, -> sR1
// MODE 3: (silu(.) + b2f(sE1b)) * scl -> outGbl
template<int MODE, int ABF16>
__device__ __forceinline__ void gemm_mfma(
    const void* A, u16* sE1b, float* sR1,
    const u16* __restrict__ Wt, const float* __restrict__ bias,
    const float* __restrict__ extraGbl, float* __restrict__ outGbl,
    float scl, int n0, int t)
{
  const int lane = t & 63;
  const int ln   = lane & 15;
  const int quad = lane >> 4;
  const int nt0  = (t >> 6) << 1;
  f32x4 acc0 = {0.f,0.f,0.f,0.f};
  f32x4 acc1 = {0.f,0.f,0.f,0.f};
  const u16* bp0 = Wt + (nt0*16 + ln)*DIM;
  const u16* bp1 = bp0 + 16*DIM;
  #pragma unroll
  for (int ks = 0; ks < 8; ks++){
    const int k0 = ks*32 + quad*8;
    bf16x8 af;
    if (ABF16){
      af = *(const bf16x8*)((const u16*)A + ln*PD2 + k0);
    } else {
      const float* arow = (const float*)A + ln*PDIM;
      float4 a01 = *(const float4*)(arow + k0);
      float4 a23 = *(const float4*)(arow + k0 + 4);
      af[0]=(short)f2b(a01.x); af[1]=(short)f2b(a01.y);
      af[2]=(short)f2b(a01.z); af[3]=(short)f2b(a01.w);
      af[4]=(short)f2b(a23.x); af[5]=(short)f2b(a23.y);
      af[6]=(short)f2b(a23.z); af[7]=(short)f2b(a23.w);
    }
    bf16x8 b0 = *(const bf16x8*)(bp0 + k0);
    bf16x8 b1 = *(const bf16x8*)(bp1 + k0);
    acc0 = __builtin_amdgcn_mfma_f32_16x16x32_bf16(af, b0, acc0, 0, 0, 0);
    acc1 = __builtin_amdgcn_mfma_f32_16x16x32_bf16(af, b1, acc1, 0, 0, 0);
  }
  if (MODE == 2) __syncthreads();   // all k-loop reads of sR1 done before overwrite
  #pragma unroll
  for (int r = 0; r < 4; r++){
    const int m = quad*4 + r;
    #pragma unroll
    for (int tt = 0; tt < 2; tt++){
      const int n = (nt0+tt)*16 + ln;
      float v = (tt ? acc1[r] : acc0[r]) + bias[n];
      if (MODE == 1) v += sR1[m*PDIM + n];
      if (MODE == 2) v += extraGbl[(size_t)(n0+m)*DIM + n];
      v = fast_silu(v);
      if (MODE == 0)      sE1b[m*PD2 + n] = f2b(v);
      else if (MODE == 3) outGbl[(size_t)(n0+m)*DIM + n] = (v + b2f(sE1b[m*PD2 + n])) * scl;
      else                sR1[m*PDIM + n] = v;
    }
  }
}

__global__ __launch_bounds__(NT, 4)
void fused_moon_kernel(
    const float* __restrict__ elec, const float* __restrict__ msg,
    const float* __restrict__ rpos, const float* __restrict__ rnb,
    const int* __restrict__ s,    const int* __restrict__ snb,
    const float* __restrict__ hinit,
    const float* __restrict__ bin,
    const float* __restrict__ eesc, const float* __restrict__ eek,
    const float* __restrict__ eeb,  const float* __restrict__ Wf,
    const float* __restrict__ bfb,
    const float* __restrict__ b1, const float* __restrict__ b2,
    const float* __restrict__ b3,
    const float* __restrict__ scalep,
    const u16* __restrict__ Wt,     // ws: 4x[256][256] bf16 + Wcat[256][32]
    float* __restrict__ out)
{
  __shared__ float sR1[ROWS*PDIM];        // elec -> hmsg -> t1 -> t2   (16.6 KB)
  __shared__ u16   sE1b[ROWS*PD2];        // elec1 bf16                  (8.25 KB)
  __shared__ u16   sBC[NNB*16*SBPITCH];   // beta bf16 (16-wide)         (15.4 KB)
  __shared__ int   sMask[ROWS*NNB];       //                             (1.5 KB)
  __shared__ float sG[8*16*SGPITCH];      // per-wave gamma transpose    (20.5 KB)
  const int t  = threadIdx.x;
  const int n0 = blockIdx.x * ROWS;

  // ---- Phase 0: stage elec rows into sR1 ----
  {
    const float4* ep = (const float4*)elec;
    #pragma unroll
    for (int h = 0; h < 2; h++){
      const int idx = t + h*NT;                 // 16 rows x 64 float4
      float4 v = ep[(size_t)n0*64 + idx];
      *(float4*)&sR1[(idx>>6)*PDIM + (idx&63)*4] = v;
    }
  }
  __syncthreads();

  // ---- GEMM1: elec1 = silu(elec @ W_in + b_in) -> sE1b ----
  gemm_mfma<0,0>(sR1, sE1b, sR1, Wt, bin, nullptr, nullptr, 0.f, n0, t);

  // ---- Phase 2a: pairwise filter -> beta (bf16, 16-wide) + mask ----
  if (t < ROWS*NNB) {
    const int rr = t / NNB;
    const int k  = t - rr*NNB;
    const int n  = n0 + rr;
    const float* rp  = rpos + n*3;
    const float* rnp = rnb + (n*NNB + k)*3;
    float dx = rnp[0] - rp[0];
    float dy = rnp[1] - rp[1];
    float dz = rnp[2] - rp[2];
    float dist = sqrtf(dx*dx + dy*dy + dz*dz + 1e-12f);
    float feats[4] = {dist, dx, dy, dz};
    float h[32];
    #pragma unroll
    for (int f4 = 0; f4 < 8; f4++){
      float4 a4 = *(const float4*)&eeb[4*f4];
      float av[4] = {a4.x, a4.y, a4.z, a4.w};
      #pragma unroll
      for (int i = 0; i < 4; i++){
        float4 kv = *(const float4*)&eek[i*32 + 4*f4];
        av[0]+=feats[i]*kv.x; av[1]+=feats[i]*kv.y; av[2]+=feats[i]*kv.z; av[3]+=feats[i]*kv.w;
      }
      h[4*f4+0]=fast_silu(av[0]); h[4*f4+1]=fast_silu(av[1]);
      h[4*f4+2]=fast_silu(av[2]); h[4*f4+3]=fast_silu(av[3]);
    }
    float env[8];
    #pragma unroll
    for (int e = 0; e < 8; e++){
      float q = dist * __builtin_amdgcn_rcpf(eesc[e]);
      env[e] = __builtin_amdgcn_exp2f(-1.44269504088896340f * q * q);
    }
    float xx = dist * (1.0f/CUTOFF);
    float cut = (dist < CUTOFF) ? (1.0f-xx)*(1.0f-xx)*(1.0f+2.0f*xx) : 0.0f;
    u16* rowp = &sBC[(k*16 + rr)*SBPITCH];
    #pragma unroll
    for (int j4 = 0; j4 < 4; j4++){
      float4 a4 = *(const float4*)&bfb[4*j4];
      float av[4] = {a4.x, a4.y, a4.z, a4.w};
      #pragma unroll
      for (int f = 0; f < 40; f++){
        float val = (f < 32) ? h[f] : env[f-32];
        float4 wv = *(const float4*)&Wf[f*16 + 4*j4];
        av[0]+=val*wv.x; av[1]+=val*wv.y; av[2]+=val*wv.z; av[3]+=val*wv.w;
      }
      ushort4 bv;
      bv.x = f2b(av[0]*cut); bv.y = f2b(av[1]*cut);
      bv.z = f2b(av[2]*cut); bv.w = f2b(av[3]*cut);
      *(ushort4*)(rowp + 4*j4) = bv;
    }
    sMask[rr*NNB + k] = (s[n] == snb[n*NNB + k]) ? 1 : 0;
  }
  __syncthreads();   // sE1b + beta + mask ready; GEMM1 reads of sR1 done

  // ---- Phase 2b: gamma via MFMA + per-wave LDS transpose; float4 hinit stream ----
  {
    const int lane = t & 63;
    const int ln   = lane & 15;
    const int quad = lane >> 4;
    const int w    = t >> 6;
    const int C0   = w << 5;                  // this wave's 32-col slice
    const u16* Wcat = Wt + 4*65536;
    bf16x8 bs0 = *(const bf16x8*)(Wcat + (C0 + ln)*32 + quad*8);
    bf16x8 bs1 = *(const bf16x8*)(Wcat + (C0 + 16 + ln)*32 + quad*8);
    float* sGw = &sG[w*16*SGPITCH];

    // consumer mapping: rowA = lane>>3 (0..7), rowB = rowA+8, 4 cols at c4
    const int rowA = lane >> 3;
    const int rowB = rowA + 8;
    const int c4   = (lane & 7) << 2;
    float e1A[4], e1B[4];
    {
      ushort4 ea = *(const ushort4*)&sE1b[rowA*PD2 + C0 + c4];
      ushort4 eb = *(const ushort4*)&sE1b[rowB*PD2 + C0 + c4];
      e1A[0]=b2f(ea.x); e1A[1]=b2f(ea.y); e1A[2]=b2f(ea.z); e1A[3]=b2f(ea.w);
      e1B[0]=b2f(eb.x); e1B[1]=b2f(eb.y); e1B[2]=b2f(eb.z); e1B[3]=b2f(eb.w);
    }
    const float* hpA = hinit + (size_t)(n0 + rowA)*NNB*DIM + C0 + c4;
    const float* hpB = hpA + (size_t)8*NNB*DIM;
    float hmA[4] = {0.f,0.f,0.f,0.f};
    float hmB[4] = {0.f,0.f,0.f,0.f};
    float4 hA = *(const float4*)(hpA);
    float4 hB = *(const float4*)(hpB);
    for (int k = 0; k < NNB; k++){
      const int kn = (k+1 < NNB) ? (k+1) : (NNB-1);
      float4 hA2 = *(const float4*)(hpA + kn*DIM);
      float4 hB2 = *(const float4*)(hpB + kn*DIM);
      // producer: A-fragment from 16-wide beta, mask folded via AND
      bf16x8 b8 = *(const bf16x8*)(&sBC[(k*16 + ln)*SBPITCH + (quad&1)*8]);
      const int mm = sMask[ln*NNB + k];
      const u16 km = (u16)((((quad>>1) ^ mm) != 0) ? 0xFFFFu : 0u);
      bf16x8 af;
      #pragma unroll
      for (int j = 0; j < 8; j++) af[j] = (short)(((u16)af[j], (u16)b8[j]) & km);
      f32x4 z = {0.f,0.f,0.f,0.f};
      f32x4 g0 = __builtin_amdgcn_mfma_f32_16x16x32_bf16(af, bs0, z, 0, 0, 0);
      f32x4 g1 = __builtin_amdgcn_mfma_f32_16x16x32_bf16(af, bs1, z, 0, 0, 0);
      __builtin_amdgcn_wave_barrier();
      #pragma unroll
      for (int r = 0; r < 4; r++){
        sGw[(quad*4+r)*SGPITCH + ln]      = g0[r];
        sGw[(quad*4+r)*SGPITCH + 16 + ln] = g1[r];
      }
      __builtin_amdgcn_wave_barrier();
      float4 gA = *(const float4*)&sGw[rowA*SGPITCH + c4];
      float4 gB = *(const float4*)&sGw[rowB*SGPITCH + c4];
      __builtin_amdgcn_wave_barrier();
      hmA[0] += fast_silu(e1A[0]+hA.x)*gA.x; hmA[1] += fast_silu(e1A[1]+hA.y)*gA.y;
      hmA[2] += fast_silu(e1A[2]+hA.z)*gA.z; hmA[3] += fast_silu(e1A[3]+hA.w)*gA.w;
      hmB[0] += fast_silu(e1B[0]+hB.x)*gB.x; hmB[1] += fast_silu(e1B[1]+hB.y)*gB.y;
      hmB[2] += fast_silu(e1B[2]+hB.z)*gB.z; hmB[3] += fast_silu(e1B[3]+hB.w)*gB.w;
      hA = hA2; hB = hB2;
    }
    *(float4*)&sR1[rowA*PDIM + C0 + c4] = make_float4(hmA[0],hmA[1],hmA[2],hmA[3]);
    *(float4*)&sR1[rowB*PDIM + C0 + c4] = make_float4(hmB[0],hmB[1],hmB[2],hmB[3]);
  }
  __syncthreads();

  const float scl = scalep[0];

  // ---- GEMM2: t1 = silu(elec1 @ W1 + b1 + hmsg) -> sR1 ----
  gemm_mfma<1,1>(sE1b, sE1b, sR1, Wt + (1<<16), b1, nullptr, nullptr, 0.f, n0, t);
  __syncthreads();
  // ---- GEMM3: t2 = silu(t1 @ W2 + b2 + msg) -> sR1 (inner barrier) ----
  gemm_mfma<2,0>(sR1, sE1b, sR1, Wt + (2<<16), b2, msg, nullptr, 0.f, n0, t);
  __syncthreads();
  // ---- GEMM4: out = (silu(t2 @ W3 + b3) + elec1) * scl ----
  gemm_mfma<3,0>(sR1, sE1b, sR1, Wt + (3<<16), b3, nullptr, out, scl, n0, t);
}

extern "C" void kernel_launch(void* const* d_in, const int* in_sizes, int n_in,
                              void* d_out, int out_size, void* d_ws, size_t ws_size,
                              hipStream_t stream) {
  (void)in_sizes; (void)n_in; (void)ws_size; (void)out_size;
  const float* elec  = (const float*)d_in[0];
  const float* msg   = (const float*)d_in[1];
  const float* rpos  = (const float*)d_in[2];
  const float* rnb   = (const float*)d_in[3];
  const int*   s     = (const int*)d_in[4];
  const int*   snb   = (const int*)d_in[5];
  const float* hinit = (const float*)d_in[6];
  const float* Win   = (const float*)d_in[7];
  const float* bin   = (const float*)d_in[8];
  const float* eesc  = (const float*)d_in[9];
  const float* eek   = (const float*)d_in[10];
  const float* eeb   = (const float*)d_in[11];
  const float* Wf    = (const float*)d_in[12];
  const float* bfb   = (const float*)d_in[13];
  const float* Wsame = (const float*)d_in[14];
  const float* Wdiff = (const float*)d_in[15];
  const float* W1    = (const float*)d_in[16];
  const float* b1    = (const float*)d_in[17];
  const float* W2    = (const float*)d_in[18];
  const float* b2    = (const float*)d_in[19];
  const float* W3    = (const float*)d_in[20];
  const float* b3    = (const float*)d_in[21];
  const float* scl   = (const float*)d_in[22];
  float* outp        = (float*)d_out;
  u16*   wt          = (u16*)d_ws;       // 528 KB used

  wprep<<<dim3(1025), dim3(256), 0, stream>>>(Win, W1, W2, W3, Wsame, Wdiff, wt);
  fused_moon_kernel<<<dim3(NEL/ROWS), dim3(NT), 0, stream>>>(
      elec, msg, rpos, rnb, s, snb, hinit,
      bin, eesc, eek, eeb, Wf, bfb,
      b1, b2, b3, scl, wt, outp);
}